// Round 13
// baseline (346.390 us; speedup 1.0000x reference)
//
#include <hip/hip_runtime.h>
#include <hip/hip_bf16.h>
#include <math.h>

typedef __hip_bfloat16 bf16;
typedef short s16x8 __attribute__((ext_vector_type(8)));
typedef float f32x4 __attribute__((ext_vector_type(4)));

#define NQ 200
#define SEQ 8
#define DM 2048
#define OUTD 1152
#define LT 28
#define M_ALL 6300
#define SM 5600
#define SN_PAD 768
#define ATT_STRIDE 720
#define N2 2304          // W viewed as [2304, 2048]
#define KP 160
#define ABLK 144         // attn per-class column block (16B-aligned)

__device__ __forceinline__ float bf2f(bf16 v) { return __bfloat162float(v); }
__device__ __forceinline__ bf16 f2bf(float v) { return __float2bfloat16(v); }
__device__ __forceinline__ float ubits2f(unsigned int u16) {
    unsigned int i = u16 << 16;
    float f; __builtin_memcpy(&f, &i, 4); return f;
}
__device__ __forceinline__ unsigned short f2bits(float f) {
    bf16 b = __float2bfloat16(f);
    unsigned short u; __builtin_memcpy(&u, &b, 2); return u;
}

__device__ const int TUP_A[LT] = {0,0,0,0,0,0,0,1,1,1,1,1,1,2,2,2,2,2,3,3,3,3,4,4,4,5,5,6};
__device__ const int TUP_B[LT] = {1,2,3,4,5,6,7,2,3,4,5,6,7,3,4,5,6,7,4,5,6,7,5,6,7,6,7,7};

// ---------------------------------------------------------------------------
// prep_k (merged wconv2 + pex, one launch — no ordering dependency since the
// pex half computes its PE values inline):
//  blocks [0,9216): [k_w | v_w] fp32 -> bf16 (2 x 1,179,648 float4);
//    blocks 0..63 also zero attn tail rows 5600..5631 (fproto's q=199 block
//    reads up to row 5604 incl. k-spill -> must be finite/zero).
//  blocks [9216, 11016): pexb[r][d] = src[n][s][d] + pe(s,d) -> bf16, with
//    pe computed on the fly (__expf/__sinf/__cosf: ~32 transcendentals per
//    thread, error << bf16 ulp; kills the pe table + its dependency).
// ---------------------------------------------------------------------------
__global__ __launch_bounds__(256) void prep_k(const float4* __restrict__ kw,
                                              const float4* __restrict__ vw,
                                              ushort4* __restrict__ o,
                                              const float* __restrict__ sup,
                                              const float* __restrict__ qry,
                                              bf16* __restrict__ pexb,
                                              bf16* __restrict__ attn_tail) {
    const int b = blockIdx.x, t = threadIdx.x;
    if (b < 9216) {
        int i = b * 256 + t;                    // 0 .. 2,359,295
        float4 v = (i < 1179648) ? kw[i] : vw[i - 1179648];
        ushort4 r;
        r.x = f2bits(v.x); r.y = f2bits(v.y); r.z = f2bits(v.z); r.w = f2bits(v.w);
        o[i] = r;
        if (b < 64)
            for (int j = b * 256 + t; j < 32 * ATT_STRIDE; j += 64 * 256)
                attn_tail[j] = f2bf(0.f);
        return;
    }
    const int r = b - 9216;                     // 0..1799
    int n, s;
    const float* src;
    if (r < 200) { n = r >> 3; s = r & 7; src = sup; }
    else { int rr = r - 200; n = rr >> 3; s = rr & 7; src = qry; }
    const float4* row = (const float4*)(src + ((size_t)n * SEQ + s) * DM);
    ushort4* orow = (ushort4*)(pexb + (size_t)r * DM);
    const float C = -9.210340371976184f / 2048.0f;   // -ln(10000)/2048
    const float sf = (float)s;
    for (int d = t; d < DM / 4; d += 256) {
        float4 a = row[d];
        float e0 = (float)(4 * d);
        float dv0 = __expf(e0 * C);
        float dv2 = __expf((e0 + 2.0f) * C);
        float a0 = sf * dv0, a2 = sf * dv2;
        ushort4 ov;
        ov.x = f2bits(a.x + __sinf(a0) * 0.1f);
        ov.y = f2bits(a.y + __cosf(a0) * 0.1f);
        ov.z = f2bits(a.z + __sinf(a2) * 0.1f);
        ov.w = f2bits(a.w + __cosf(a2) * 0.1f);
        orow[d] = ov;
    }
}

// ---------------------------------------------------------------------------
// Generic MFMA bf16 GEMM: C = scale*A*B^T; z shifts A/B/C by aZ/bZ/cZ elems.
// Schedule: reg stage -> sync -> LDS write -> sync -> ds_read -> MFMA, single
// LDS buffer (compiler gives implicit 1-deep pipeline; every explicit
// reschedule lost — see r0-r5 ledger).
// r13: BK=64 — one staged tile covers 64 K-elems: same loads/writes/ds_reads/
// MFMA per K-element as BK=32 but HALF the barriers (the measured stall: ~550
// ns per 32-K step vs ~80 cy MFMA issue at 2.1 blocks/CU).  LDS 32 KB
// (m132's BK=128 failure was the 64 KB occupancy cliff; no cliff here).
// REQUIRES K % 64 == 0 (call sites: 2048, 1152).
// Templated N-tile (r6/r7/r8 measured): TN=128 projection, TN=64 scores.
// XCD-chunked bijective block swizzle kept (FETCH 104->42 MB measured).
// C rows >= mlim are not stored (M-pad garbage containment).
// ---------------------------------------------------------------------------
template <int TN>
__global__ __launch_bounds__(256) void gemm_bt(
    const bf16* __restrict__ A, int lda, size_t aZ,
    const bf16* __restrict__ B, int ldb, size_t bZ,
    float scale, bf16* __restrict__ C, int ldc, size_t cZ, int K, int mlim) {
    constexpr int JN = TN / 32;            // B-frags per wave (2 or 4)
    // ---- XCD swizzle: logical tile id lg from hw block id (bijective) ----
    const int gx = gridDim.x, gy = gridDim.y;
    const int nwg = gx * gy * (int)gridDim.z;
    const int orig = ((int)blockIdx.z * gy + blockIdx.y) * gx + blockIdx.x;
    const int qc = nwg >> 3, rc = nwg & 7;
    const int xcd = orig & 7, sub = orig >> 3;
    const int lg = (xcd < rc ? xcd * (qc + 1) : rc * (qc + 1) + (xcd - rc) * qc) + sub;
    const int bx = lg % gx;
    const int rest = lg / gx;
    const int by = rest % gy, bz = rest / gy;

    const unsigned short* Ag0 = (const unsigned short*)A + aZ * bz;
    const unsigned short* Bg0 = (const unsigned short*)B + bZ * bz;
    const size_t cbase = cZ * bz;
    const int tile_m = bx * 128, tile_n = by * TN;
    __shared__ unsigned short As[8 * 128 * 8];     // 16 KB
    __shared__ unsigned short Bs[8 * TN * 8];      // 16/8 KB
    const int t = threadIdx.x, lane = t & 63, wave = t >> 6;
    const int wm = (wave & 1) * 64, wn = (wave >> 1) * (TN / 2);
    const int fr = lane & 15, quad = lane >> 4;

    // A staging: thread t owns (row0 = t&127, kq0 = t>>7), 4 slots kq0+{0,2,4,6}
    const int row0 = t & 127, kq0 = t >> 7;
    const unsigned short* Ag = Ag0 + (size_t)(tile_m + row0) * lda + kq0 * 8;
    unsigned short* AsW = &As[(kq0 * 128 + row0) * 8];
    // B staging
    const unsigned short* Bg;
    unsigned short* BsW;
    if constexpr (TN == 128) {             // (row0, kq0), slots kq0+{0,2,4,6}
        Bg = Bg0 + (size_t)(tile_n + row0) * ldb + kq0 * 8;
        BsW = &Bs[(kq0 * 128 + row0) * 8];
    } else {                               // (brow = t&63, bkq = t>>6), slots bkq+{0,4}
        const int brow = t & 63, bkq = t >> 6;
        Bg = Bg0 + (size_t)(tile_n + brow) * ldb + bkq * 8;
        BsW = &Bs[(bkq * 64 + brow) * 8];
    }

    f32x4 acc[4][JN];
#pragma unroll
    for (int i = 0; i < 4; i++)
#pragma unroll
        for (int j = 0; j < JN; j++) acc[i][j] = {0.f, 0.f, 0.f, 0.f};

    for (int k0 = 0; k0 < K; k0 += 64) {
        uint4 a0 = *(const uint4*)(Ag + k0);
        uint4 a1 = *(const uint4*)(Ag + k0 + 16);
        uint4 a2 = *(const uint4*)(Ag + k0 + 32);
        uint4 a3 = *(const uint4*)(Ag + k0 + 48);
        uint4 b0, b1, b2, b3;
        if constexpr (TN == 128) {
            b0 = *(const uint4*)(Bg + k0);
            b1 = *(const uint4*)(Bg + k0 + 16);
            b2 = *(const uint4*)(Bg + k0 + 32);
            b3 = *(const uint4*)(Bg + k0 + 48);
        } else {
            b0 = *(const uint4*)(Bg + k0);
            b1 = *(const uint4*)(Bg + k0 + 32);
        }
        __syncthreads();                    // prev readers done
        *(uint4*)(AsW + 0)    = a0;         // kq0
        *(uint4*)(AsW + 2048) = a1;         // kq0+2  (2*128*8 shorts)
        *(uint4*)(AsW + 4096) = a2;         // kq0+4
        *(uint4*)(AsW + 6144) = a3;         // kq0+6
        if constexpr (TN == 128) {
            *(uint4*)(BsW + 0)    = b0;
            *(uint4*)(BsW + 2048) = b1;
            *(uint4*)(BsW + 4096) = b2;
            *(uint4*)(BsW + 6144) = b3;
        } else {
            *(uint4*)(BsW + 0)    = b0;     // bkq
            *(uint4*)(BsW + 2048) = b1;     // bkq+4  (4*64*8 shorts)
        }
        __syncthreads();                    // tile visible
#pragma unroll
        for (int s = 0; s < 2; s++) {
            s16x8 af[4], bfv[JN];
#pragma unroll
            for (int i = 0; i < 4; i++)
                af[i] = *(const s16x8*)&As[((s * 4 + quad) * 128 + wm + i * 16 + fr) * 8];
#pragma unroll
            for (int j = 0; j < JN; j++)
                bfv[j] = *(const s16x8*)&Bs[((s * 4 + quad) * TN + wn + j * 16 + fr) * 8];
#pragma unroll
            for (int i = 0; i < 4; i++)
#pragma unroll
                for (int j = 0; j < JN; j++)
                    acc[i][j] = __builtin_amdgcn_mfma_f32_16x16x32_bf16(af[i], bfv[j], acc[i][j], 0, 0, 0);
        }
    }

    const int rb = quad * 4;
#pragma unroll
    for (int i = 0; i < 4; i++)
#pragma unroll
        for (int j = 0; j < JN; j++) {
            const int col = tile_n + wn + j * 16 + fr;
#pragma unroll
            for (int r = 0; r < 4; r++) {
                const int row = tile_m + wm + i * 16 + rb + r;
                if (row < mlim)
                    C[cbase + (size_t)row * ldc + col] = f2bf(acc[i][j][r] * scale);
            }
        }
}

// ---------------------------------------------------------------------------
// combine_kv (merged, one launch): blocks [0,M_ALL) -> K path (LN),
// blocks [M_ALL, 2*M_ALL) -> V path.  G13-vectorized (uint4/float4/ushort4),
// per-path XCD-chunked bijective swizzle (r9, measured win).
// ---------------------------------------------------------------------------
__global__ __launch_bounds__(256) void combine_kv(
    const unsigned int* __restrict__ Yk, const unsigned int* __restrict__ Yv,
    const float* __restrict__ kb, const float* __restrict__ vb,
    const float* __restrict__ lng, const float* __restrict__ lnb,
    bf16* __restrict__ ks, bf16* __restrict__ vs) {
    const int t = threadIdx.x, lane = t & 63, wave = t >> 6;
    int orig = blockIdx.x;
    const bool vpath = orig >= M_ALL;
    if (vpath) orig -= M_ALL;
    {
        const int qc = M_ALL >> 3, rc = M_ALL & 7;
        const int xcd = orig & 7, sub = orig >> 3;
        orig = (xcd < rc ? xcd * (qc + 1) : rc * (qc + 1) + (xcd - rc) * qc) + sub;
    }
    const int m = orig;
    int mm = m < 700 ? m : m - 700;
    int base = m < 700 ? 0 : 200;
    int nsamp = mm / LT, l = mm - nsamp * LT;
    const unsigned int* Y = vpath ? Yv : Yk;
    const uint4* ya4 = (const uint4*)(Y + (size_t)(base + nsamp * 8 + TUP_A[l]) * (N2 / 2));
    const uint4* yb4 = (const uint4*)(Y + (size_t)(base + nsamp * 8 + TUP_B[l]) * (N2 / 2));
    if (vpath) {
        const float4* vb4 = (const float4*)vb;
        for (int u = t; u < OUTD / 4; u += 256) {       // 288 slots
            uint4 a4 = ya4[u], b4 = yb4[u];
            float4 c4 = vb4[u];
            ushort4 o;
            o.x = f2bits(ubits2f(a4.x & 0xFFFFu) + ubits2f(b4.x >> 16) + c4.x);
            o.y = f2bits(ubits2f(a4.y & 0xFFFFu) + ubits2f(b4.y >> 16) + c4.y);
            o.z = f2bits(ubits2f(a4.z & 0xFFFFu) + ubits2f(b4.z >> 16) + c4.z);
            o.w = f2bits(ubits2f(a4.w & 0xFFFFu) + ubits2f(b4.w >> 16) + c4.w);
            *(ushort4*)&vs[(size_t)m * OUTD + u * 4] = o;
        }
        return;
    }
    const float4* kb4 = (const float4*)kb;
    float vals[8];                                      // <= 2 iters x 4
    int cnt = 0;
    float s = 0.f, s2 = 0.f;
    for (int u = t; u < OUTD / 4; u += 256) {
        uint4 a4 = ya4[u], b4 = yb4[u];
        float4 c4 = kb4[u];
        float v0 = ubits2f(a4.x & 0xFFFFu) + ubits2f(b4.x >> 16) + c4.x;
        float v1 = ubits2f(a4.y & 0xFFFFu) + ubits2f(b4.y >> 16) + c4.y;
        float v2 = ubits2f(a4.z & 0xFFFFu) + ubits2f(b4.z >> 16) + c4.z;
        float v3 = ubits2f(a4.w & 0xFFFFu) + ubits2f(b4.w >> 16) + c4.w;
        vals[cnt] = v0; vals[cnt + 1] = v1; vals[cnt + 2] = v2; vals[cnt + 3] = v3;
        cnt += 4;
        s += (v0 + v1) + (v2 + v3);
        s2 += v0 * v0 + v1 * v1 + v2 * v2 + v3 * v3;
    }
    for (int o = 32; o > 0; o >>= 1) { s += __shfl_xor(s, o); s2 += __shfl_xor(s2, o); }
    __shared__ float r1[4], r2[4];
    if (lane == 0) { r1[wave] = s; r2[wave] = s2; }
    __syncthreads();
    s = r1[0] + r1[1] + r1[2] + r1[3];
    s2 = r2[0] + r2[1] + r2[2] + r2[3];
    float mu = s * (1.f / OUTD);
    float var = s2 * (1.f / OUTD) - mu * mu;
    float inv = rsqrtf(fmaxf(var, 0.f) + 1e-5f);
    const float4* lg4 = (const float4*)lng;
    const float4* lb4 = (const float4*)lnb;
    cnt = 0;
    for (int u = t; u < OUTD / 4; u += 256) {
        float4 g4 = lg4[u], b4v = lb4[u];
        ushort4 o;
        o.x = f2bits((vals[cnt]     - mu) * inv * g4.x + b4v.x);
        o.y = f2bits((vals[cnt + 1] - mu) * inv * g4.y + b4v.y);
        o.z = f2bits((vals[cnt + 2] - mu) * inv * g4.z + b4v.z);
        o.w = f2bits((vals[cnt + 3] - mu) * inv * g4.w + b4v.w);
        cnt += 4;
        *(ushort4*)&ks[(size_t)m * OUTD + u * 4] = o;
    }
}

// ---------------------------------------------------------------------------
// sv_k (merged softmax + vspad, one launch, 320 threads):
//  blocks [0,SM): softmax, one WAVE per (row, class), barrier-free
//    (140 = 64+64+12 lane-slots; attn as 5 x 144-col blocks, pad zeroed).
//  blocks [SM, SM+2880): vsp[w][d][j] = vs[w*140+j][d] (j>=140 -> 0);
//    block SM also zeroes gbuf.  2880*320 == 5*OUTD*KP exactly.
// ---------------------------------------------------------------------------
__global__ __launch_bounds__(320) void sv_k(const bf16* __restrict__ sc,
                                            bf16* __restrict__ attn,
                                            const bf16* __restrict__ vs,
                                            bf16* __restrict__ vp,
                                            float* __restrict__ gbuf) {
    const int t = threadIdx.x;
    if (blockIdx.x < SM) {
        const int row = blockIdx.x, w = t >> 6, lane = t & 63;
        const bf16* src = sc + (size_t)row * SN_PAD + w * 140;
        bf16* dst = attn + (size_t)row * ATT_STRIDE + w * ABLK;
        float a = bf2f(src[lane]);
        float b = bf2f(src[lane + 64]);        // lane+64 <= 127 < 140: valid
        float c = (lane < 12) ? bf2f(src[lane + 128]) : -3.0e38f;
        float m = fmaxf(fmaxf(a, b), c);
        for (int o = 32; o > 0; o >>= 1) m = fmaxf(m, __shfl_xor(m, o));
        float ea = __expf(a - m), eb = __expf(b - m);
        float ec = (lane < 12) ? __expf(c - m) : 0.f;
        float s = ea + eb + ec;
        for (int o = 32; o > 0; o >>= 1) s += __shfl_xor(s, o);
        float inv = 1.f / s;
        dst[lane] = f2bf(ea * inv);
        dst[lane + 64] = f2bf(eb * inv);
        if (lane < 16) dst[lane + 128] = f2bf(lane < 12 ? ec * inv : 0.f);
        return;
    }
    const int vb = blockIdx.x - SM;            // 0..2879
    if (vb == 0)
        for (int i = t; i < NQ * 21; i += 320) gbuf[i] = 0.f;
    int idx = vb * 320 + t;                    // < 921600 == 5*OUTD*KP
    int j = idx % KP;
    int rest = idx / KP;
    int dcol = rest % OUTD;
    int w = rest / OUTD;
    vp[idx] = (j < 140) ? vs[(size_t)(w * 140 + j) * OUTD + dcol] : f2bf(0.f);
}

// ---------------------------------------------------------------------------
// fproto_k v2: FUSED proto-GEMM + Gram reduction (r11/r12, verified).
// One block = one (query q, d-tile of 128).  Grid 1800, q-major XCD swizzle.
// A (attn rows) for ALL 5 classes staged once (50KB LDS, 2 barriers total);
// B (vsp) fragments read directly global->VGPR (zero cross-wave sharing;
// vsp L2-resident).  M=32 pads 28 real l-rows; l>=28 excluded from stats.
// K in [140,160) multiplies vsp's zero cols; max A read = attn row 5604
// (zeroed tail).  Epilogue: per-lane 21 stats, wave shfl + LDS reduce,
// 21 atomicAdds to gbuf[q*21..].  fp32 end-to-end.
// ---------------------------------------------------------------------------
__global__ __launch_bounds__(256) void fproto_k(
    const bf16* __restrict__ attn,   // [5632][720]
    const bf16* __restrict__ vsp,    // [5][1152][160]
    const bf16* __restrict__ vs,     // [6300][1152]
    float* __restrict__ gbuf) {      // [200][21]
    const int nwg = gridDim.x;       // 1800
    int orig = blockIdx.x;
    {
        const int qc = nwg >> 3, rc = nwg & 7;
        const int xcd = orig & 7, sub = orig >> 3;
        orig = (xcd < rc ? xcd * (qc + 1) : rc * (qc + 1) + (xcd - rc) * qc) + sub;
    }
    const int q = orig / 9, dt = orig - q * 9;
    const int t = threadIdx.x, lane = t & 63, wave = t >> 6;
    const int fr = lane & 15, quad = lane >> 4;

    __shared__ unsigned short As5[5 * 20 * 32 * 8];   // 51,200 B
    __shared__ float red[4][21];

    const unsigned short* attn_u = (const unsigned short*)attn;
    const unsigned short* vsp_u = (const unsigned short*)vsp;

    // stage ALL classes' A once: slot = w*640 + kq*32 + row  (3200 slots)
    for (int slot = t; slot < 3200; slot += 256) {
        int w = slot / 640, rem = slot - w * 640;
        int kq = rem >> 5, row = rem & 31;
        *(uint4*)&As5[slot * 8] =
            *(const uint4*)&attn_u[(size_t)(q * 28 + row) * ATT_STRIDE + w * ABLK + kq * 8];
    }
    __syncthreads();

    f32x4 acc[5][2][2];
#pragma unroll
    for (int w = 0; w < 5; w++)
#pragma unroll
        for (int i = 0; i < 2; i++)
#pragma unroll
            for (int j = 0; j < 2; j++) acc[w][i][j] = {0.f, 0.f, 0.f, 0.f};

    // per-lane B base: row (dt*128 + wave*32 + fr), kq-offset quad*8
    const unsigned short* vbase =
        vsp_u + (size_t)(dt * 128 + wave * 32 + fr) * KP + quad * 8;

#pragma unroll
    for (int w = 0; w < 5; w++) {
        s16x8 bfv[5][2];                        // issue all 10 loads up-front
#pragma unroll
        for (int s = 0; s < 5; s++)
#pragma unroll
            for (int j = 0; j < 2; j++)
                bfv[s][j] = *(const s16x8*)(vbase
                    + (size_t)w * OUTD * KP + (size_t)j * 16 * KP + s * 32);
#pragma unroll
        for (int s = 0; s < 5; s++) {
            s16x8 af[2];
#pragma unroll
            for (int i = 0; i < 2; i++)
                af[i] = *(const s16x8*)&As5[(w * 640 + (s * 4 + quad) * 32 + i * 16 + fr) * 8];
#pragma unroll
            for (int i = 0; i < 2; i++)
#pragma unroll
                for (int j = 0; j < 2; j++)
                    acc[w][i][j] = __builtin_amdgcn_mfma_f32_16x16x32_bf16(af[i], bfv[s][j], acc[w][i][j], 0, 0, 0);
        }
    }

    // ---- stats epilogue: C[l = i*16+quad*4+r][col = wave*32+j*16+fr] ----
    float st[21];
#pragma unroll
    for (int k = 0; k < 21; k++) st[k] = 0.f;
#pragma unroll
    for (int i = 0; i < 2; i++)
#pragma unroll
        for (int r = 0; r < 4; r++) {
            const int l = i * 16 + quad * 4 + r;
            if (l < 28) {
                const size_t vrow = (size_t)(700 + q * 28 + l) * OUTD;
#pragma unroll
                for (int j = 0; j < 2; j++) {
                    const int col = dt * 128 + wave * 32 + j * 16 + fr;
                    float v = bf2f(vs[vrow + col]);
                    float pv[5];
#pragma unroll
                    for (int w = 0; w < 5; w++) pv[w] = acc[w][i][j][r];
                    st[20] += v * v;
                    int c = 0;
#pragma unroll
                    for (int a = 0; a < 5; a++) {
                        st[15 + a] += v * pv[a];
#pragma unroll
                        for (int b = a; b < 5; b++) st[c++] += pv[a] * pv[b];
                    }
                }
            }
        }
#pragma unroll
    for (int k = 0; k < 21; k++)
        for (int o = 32; o > 0; o >>= 1) st[k] += __shfl_xor(st[k], o);
    if (lane == 0)
#pragma unroll
        for (int k = 0; k < 21; k++) red[wave][k] = st[k];
    __syncthreads();
    if (t < 21)
        atomicAdd(&gbuf[q * 21 + t], red[0][t] + red[1][t] + red[2][t] + red[3][t]);
}

// ---------------------------------------------------------------------------
// out (fp32): per q -> 25 sim + 5 ori
// ---------------------------------------------------------------------------
__global__ __launch_bounds__(64) void out_k(const float* __restrict__ gbuf,
                                            float* __restrict__ out) {
    int q = blockIdx.x;
    if (threadIdx.x != 0) return;
    const float* r = gbuf + q * 21;
    float G[5][5];
    int c = 0;
    for (int a = 0; a < 5; a++)
        for (int b = a; b < 5; b++) { G[a][b] = r[c]; G[b][a] = r[c]; c++; }
    float e = r[20];
    float nrm[5];
    for (int a = 0; a < 5; a++) nrm[a] = sqrtf(fmaxf(G[a][a], 0.f));
    for (int a = 0; a < 5; a++)
        for (int b = 0; b < 5; b++)
            out[(size_t)q * 25 + a * 5 + b] = G[a][b] / fmaxf(nrm[a] * nrm[b], 1e-8f);
    for (int w = 0; w < 5; w++)
        out[5000 + (size_t)q * 5 + w] = -(e - 2.f * r[15 + w] + G[w][w]) * (1.f / 28.f);
}

// ---------------------------------------------------------------------------
extern "C" void kernel_launch(void* const* d_in, const int* in_sizes, int n_in,
                              void* d_out, int out_size, void* d_ws, size_t ws_size,
                              hipStream_t stream) {
    const float* sup = (const float*)d_in[0];
    // d_in[1] = support_labels int32 — unused (sorted equal-shot)
    const float* qry = (const float*)d_in[2];
    const float* k_w = (const float*)d_in[3];
    const float* k_b = (const float*)d_in[4];
    const float* v_w = (const float*)d_in[5];
    const float* v_b = (const float*)d_in[6];
    const float* lng = (const float*)d_in[7];
    const float* lnb = (const float*)d_in[8];
    (void)in_sizes; (void)n_in; (void)out_size; (void)ws_size;

    // layout (bytes), peak 49,356,192 (<= verified ws_size >= 54.5 MB):
    //   pexb   @0           7,864,320 (1920 rows; 1800 real)  dead after proj
    //   wbf    @7,864,320  18,874,368 (k|v bf16)              dead after proj
    //   Yk     @26,738,688  8,294,400 (1800x2304)             dead after comb_k
    //   Yv     @35,033,088  8,294,400                         dead after comb_v
    //   ks     @0          14,588,928 (6332 rows; 6300 real)  dead after scores
    //   vs     @16,220,160 14,515,200 (6300 rows)             live to end
    //   sc     @30,735,360  8,650,752 (over dead Yk/Yv head)  dead after softmax
    //   vsp    @39,386,112  1,843,200
    //   attn   @41,229,312  8,110,080 (5632 rows x 720; 5 x 144-col blocks)
    //   gbuf   @49,339,392     16,800
    //   (pe table eliminated — prep_k computes PE inline)
    //   (protoc eliminated — fproto_k keeps proto in registers)
    char* ws = (char*)d_ws;
    bf16* pexb   = (bf16*)(ws + 0);
    bf16* wbf    = (bf16*)(ws + 7864320);
    bf16* Yk     = (bf16*)(ws + 26738688);
    bf16* Yv     = (bf16*)(ws + 35033088);
    bf16* ks     = (bf16*)(ws + 0);
    bf16* vs     = (bf16*)(ws + 16220160);
    bf16* sc     = (bf16*)(ws + 30735360);
    bf16* vsp    = (bf16*)(ws + 39386112);
    bf16* attn   = (bf16*)(ws + 41229312);
    float* gbuf  = (float*)(ws + 49339392);

    // merged wconv + pex (pex computes PE inline; also zeroes attn tail)
    prep_k<<<dim3(9216 + 1800), dim3(256), 0, stream>>>(
        (const float4*)k_w, (const float4*)v_w, (ushort4*)wbf,
        sup, qry, pexb, attn + (size_t)SM * ATT_STRIDE);

    // fused K+V projection: z in {k,v}; Y[1800,2304] = pexb @ W_view^T
    // TN=128 (r6/r8: 71.7us vs 84 at TN=64); BK=64 halves barrier count.
    gemm_bt<128><<<dim3(15, 18, 2), dim3(256), 0, stream>>>(
        pexb, DM, 0, wbf, DM, (size_t)4718592,
        1.0f, Yk, N2, (size_t)4147200, DM, 1800);

    combine_kv<<<dim3(2 * M_ALL), dim3(256), 0, stream>>>(
        (const unsigned int*)Yk, (const unsigned int*)Yv,
        k_b, v_b, lng, lnb, ks, vs);

    // scores: ks_q[5632,1152] @ ks_s[768,1152]^T / sqrt(1152)  (TN=64, r7)
    gemm_bt<64><<<dim3(44, 12, 1), dim3(256), 0, stream>>>(
        ks + (size_t)700 * OUTD, OUTD, 0, ks, OUTD, 0,
        0.029462782549439484f, sc, SN_PAD, 0, OUTD, 5632);

    // merged softmax (5600 blocks) + vspad (2880 blocks), 320 threads
    sv_k<<<dim3(SM + 2880), dim3(320), 0, stream>>>(sc, attn, vs, vsp, gbuf);

    // fused proto + Gram stats: one launch replaces 4x(gemm+gramred)
    fproto_k<<<dim3(1800), dim3(256), 0, stream>>>(attn, vsp, vs, gbuf);

    out_k<<<dim3(NQ), dim3(64), 0, stream>>>(gbuf, (float*)d_out);
}

// Round 14
// 287.791 us; speedup vs baseline: 1.2036x; 1.2036x over previous
//
#include <hip/hip_runtime.h>
#include <hip/hip_bf16.h>
#include <math.h>

typedef __hip_bfloat16 bf16;
typedef short s16x8 __attribute__((ext_vector_type(8)));
typedef float f32x4 __attribute__((ext_vector_type(4)));

#define NQ 200
#define SEQ 8
#define DM 2048
#define OUTD 1152
#define LT 28
#define M_ALL 6300
#define SM 5600
#define SN_PAD 768
#define ATT_STRIDE 720
#define N2 2304          // W viewed as [2304, 2048]
#define KP 160
#define ABLK 144         // attn per-class column block (16B-aligned)

__device__ __forceinline__ float bf2f(bf16 v) { return __bfloat162float(v); }
__device__ __forceinline__ bf16 f2bf(float v) { return __float2bfloat16(v); }
__device__ __forceinline__ float ubits2f(unsigned int u16) {
    unsigned int i = u16 << 16;
    float f; __builtin_memcpy(&f, &i, 4); return f;
}
__device__ __forceinline__ unsigned short f2bits(float f) {
    bf16 b = __float2bfloat16(f);
    unsigned short u; __builtin_memcpy(&u, &b, 2); return u;
}

__device__ const int TUP_A[LT] = {0,0,0,0,0,0,0,1,1,1,1,1,1,2,2,2,2,2,3,3,3,3,4,4,4,5,5,6};
__device__ const int TUP_B[LT] = {1,2,3,4,5,6,7,2,3,4,5,6,7,3,4,5,6,7,4,5,6,7,5,6,7,6,7,7};

// ---------------------------------------------------------------------------
// prep_k (merged wconv2 + pex, one launch):
//  blocks [0,9216): [k_w | v_w] fp32 -> bf16; blocks 0..63 also zero attn
//    tail rows 5600..5631 (fproto's q=199 block reads up to row 5604).
//  blocks [9216, 11016): pexb[r][d] = src[n][s][d] + pe(s,d) -> bf16, PE
//    computed inline (__expf/__sinf/__cosf, error << bf16 ulp).
// ---------------------------------------------------------------------------
__global__ __launch_bounds__(256) void prep_k(const float4* __restrict__ kw,
                                              const float4* __restrict__ vw,
                                              ushort4* __restrict__ o,
                                              const float* __restrict__ sup,
                                              const float* __restrict__ qry,
                                              bf16* __restrict__ pexb,
                                              bf16* __restrict__ attn_tail) {
    const int b = blockIdx.x, t = threadIdx.x;
    if (b < 9216) {
        int i = b * 256 + t;                    // 0 .. 2,359,295
        float4 v = (i < 1179648) ? kw[i] : vw[i - 1179648];
        ushort4 r;
        r.x = f2bits(v.x); r.y = f2bits(v.y); r.z = f2bits(v.z); r.w = f2bits(v.w);
        o[i] = r;
        if (b < 64)
            for (int j = b * 256 + t; j < 32 * ATT_STRIDE; j += 64 * 256)
                attn_tail[j] = f2bf(0.f);
        return;
    }
    const int r = b - 9216;                     // 0..1799
    int n, s;
    const float* src;
    if (r < 200) { n = r >> 3; s = r & 7; src = sup; }
    else { int rr = r - 200; n = rr >> 3; s = rr & 7; src = qry; }
    const float4* row = (const float4*)(src + ((size_t)n * SEQ + s) * DM);
    ushort4* orow = (ushort4*)(pexb + (size_t)r * DM);
    const float C = -9.210340371976184f / 2048.0f;   // -ln(10000)/2048
    const float sf = (float)s;
    for (int d = t; d < DM / 4; d += 256) {
        float4 a = row[d];
        float e0 = (float)(4 * d);
        float dv0 = __expf(e0 * C);
        float dv2 = __expf((e0 + 2.0f) * C);
        float a0 = sf * dv0, a2 = sf * dv2;
        ushort4 ov;
        ov.x = f2bits(a.x + __sinf(a0) * 0.1f);
        ov.y = f2bits(a.y + __cosf(a0) * 0.1f);
        ov.z = f2bits(a.z + __sinf(a2) * 0.1f);
        ov.w = f2bits(a.w + __cosf(a2) * 0.1f);
        orow[d] = ov;
    }
}

// ---------------------------------------------------------------------------
// Generic MFMA bf16 GEMM: C = scale*A*B^T; z shifts A/B/C by aZ/bZ/cZ elems.
// Schedule: reg stage -> sync -> LDS write -> sync -> ds_read -> MFMA, single
// LDS buffer (r12 baseline, 74us/289.7 total verified).
// r14: BK=64 done RIGHT — r13 regressed because its new staging map put 1
// lane/row (16B used per 4KB-strided line, G2 violation; proj 74->114us).
// This version keeps r12's EXACT per-instruction address pattern (srow=t>>1,
// (t&1)*16 k-offset; 2 lanes cover one 64B line) and applies it TWICE per
// barrier pair (second half at k0+32 -> LDS kq-slots 4..7).  Only delta vs
// r12: HALF the barriers.  Bitwise-same C (K-accum order unchanged).
// REQUIRES K % 64 == 0 (call sites: 2048, 1152).
// TN=128 projection / TN=64 scores (r6/r7/r8 measured).
// XCD-chunked bijective block swizzle kept (FETCH 104->42 MB measured).
// C rows >= mlim are not stored (M-pad garbage containment).
// ---------------------------------------------------------------------------
template <int TN>
__global__ __launch_bounds__(256) void gemm_bt(
    const bf16* __restrict__ A, int lda, size_t aZ,
    const bf16* __restrict__ B, int ldb, size_t bZ,
    float scale, bf16* __restrict__ C, int ldc, size_t cZ, int K, int mlim) {
    constexpr int JN = TN / 32;            // B-frags per wave (2 or 4)
    // ---- XCD swizzle: logical tile id lg from hw block id (bijective) ----
    const int gx = gridDim.x, gy = gridDim.y;
    const int nwg = gx * gy * (int)gridDim.z;
    const int orig = ((int)blockIdx.z * gy + blockIdx.y) * gx + blockIdx.x;
    const int qc = nwg >> 3, rc = nwg & 7;
    const int xcd = orig & 7, sub = orig >> 3;
    const int lg = (xcd < rc ? xcd * (qc + 1) : rc * (qc + 1) + (xcd - rc) * qc) + sub;
    const int bx = lg % gx;
    const int rest = lg / gx;
    const int by = rest % gy, bz = rest / gy;

    const unsigned short* Ag0 = (const unsigned short*)A + aZ * bz;
    const unsigned short* Bg0 = (const unsigned short*)B + bZ * bz;
    const size_t cbase = cZ * bz;
    const int tile_m = bx * 128, tile_n = by * TN;
    __shared__ unsigned short As[8 * 128 * 8];     // 16 KB
    __shared__ unsigned short Bs[8 * TN * 8];      // 16/8 KB
    const int t = threadIdx.x, lane = t & 63, wave = t >> 6;
    const int wm = (wave & 1) * 64, wn = (wave >> 1) * (TN / 2);
    const int srow = t >> 1, sq0 = (t & 1) * 2;
    const unsigned short* Ag = Ag0 + (size_t)(tile_m + srow) * lda + (t & 1) * 16;
    unsigned short* AsW0 = &As[((sq0 + 0) * 128 + srow) * 8];
    unsigned short* AsW1 = &As[((sq0 + 1) * 128 + srow) * 8];
    unsigned short* AsW2 = &As[((sq0 + 4) * 128 + srow) * 8];
    unsigned short* AsW3 = &As[((sq0 + 5) * 128 + srow) * 8];
    const unsigned short* Bg;
    unsigned short* BsW0;
    unsigned short* BsW1 = nullptr;
    unsigned short* BsW2;
    unsigned short* BsW3 = nullptr;
    if constexpr (TN == 128) {             // r12 map, applied to both halves
        Bg = Bg0 + (size_t)(tile_n + srow) * ldb + (t & 1) * 16;
        BsW0 = &Bs[((sq0 + 0) * 128 + srow) * 8];
        BsW1 = &Bs[((sq0 + 1) * 128 + srow) * 8];
        BsW2 = &Bs[((sq0 + 4) * 128 + srow) * 8];
        BsW3 = &Bs[((sq0 + 5) * 128 + srow) * 8];
    } else {                               // r12 map (brow=t&63, bkq=t>>6)
        const int brow = t & 63, bkq = t >> 6;
        Bg = Bg0 + (size_t)(tile_n + brow) * ldb + bkq * 8;
        BsW0 = &Bs[(bkq * 64 + brow) * 8];
        BsW2 = &Bs[((bkq + 4) * 64 + brow) * 8];
    }
    const int fr = lane & 15, quad = lane >> 4;

    f32x4 acc[4][JN];
#pragma unroll
    for (int i = 0; i < 4; i++)
#pragma unroll
        for (int j = 0; j < JN; j++) acc[i][j] = {0.f, 0.f, 0.f, 0.f};

    for (int k0 = 0; k0 < K; k0 += 64) {
        uint4 a0 = *(const uint4*)(Ag + k0);
        uint4 a1 = *(const uint4*)(Ag + k0 + 8);
        uint4 a2 = *(const uint4*)(Ag + k0 + 32);
        uint4 a3 = *(const uint4*)(Ag + k0 + 40);
        uint4 b0, b1, b2, b3;
        if constexpr (TN == 128) {
            b0 = *(const uint4*)(Bg + k0);
            b1 = *(const uint4*)(Bg + k0 + 8);
            b2 = *(const uint4*)(Bg + k0 + 32);
            b3 = *(const uint4*)(Bg + k0 + 40);
        } else {
            b0 = *(const uint4*)(Bg + k0);
            b2 = *(const uint4*)(Bg + k0 + 32);
        }
        __syncthreads();                    // prev readers done
        *(uint4*)AsW0 = a0; *(uint4*)AsW1 = a1;
        *(uint4*)AsW2 = a2; *(uint4*)AsW3 = a3;
        if constexpr (TN == 128) {
            *(uint4*)BsW0 = b0; *(uint4*)BsW1 = b1;
            *(uint4*)BsW2 = b2; *(uint4*)BsW3 = b3;
        } else {
            *(uint4*)BsW0 = b0; *(uint4*)BsW2 = b2;
        }
        __syncthreads();                    // tile visible
#pragma unroll
        for (int s = 0; s < 2; s++) {
            s16x8 af[4], bfv[JN];
#pragma unroll
            for (int i = 0; i < 4; i++)
                af[i] = *(const s16x8*)&As[((s * 4 + quad) * 128 + wm + i * 16 + fr) * 8];
#pragma unroll
            for (int j = 0; j < JN; j++)
                bfv[j] = *(const s16x8*)&Bs[((s * 4 + quad) * TN + wn + j * 16 + fr) * 8];
#pragma unroll
            for (int i = 0; i < 4; i++)
#pragma unroll
                for (int j = 0; j < JN; j++)
                    acc[i][j] = __builtin_amdgcn_mfma_f32_16x16x32_bf16(af[i], bfv[j], acc[i][j], 0, 0, 0);
        }
    }

    const int rb = quad * 4;
#pragma unroll
    for (int i = 0; i < 4; i++)
#pragma unroll
        for (int j = 0; j < JN; j++) {
            const int col = tile_n + wn + j * 16 + fr;
#pragma unroll
            for (int r = 0; r < 4; r++) {
                const int row = tile_m + wm + i * 16 + rb + r;
                if (row < mlim)
                    C[cbase + (size_t)row * ldc + col] = f2bf(acc[i][j][r] * scale);
            }
        }
}

// ---------------------------------------------------------------------------
// combine_kv (merged, one launch): blocks [0,M_ALL) -> K path (LN),
// blocks [M_ALL, 2*M_ALL) -> V path.  G13-vectorized (uint4/float4/ushort4),
// per-path XCD-chunked bijective swizzle (r9, measured win).
// ---------------------------------------------------------------------------
__global__ __launch_bounds__(256) void combine_kv(
    const unsigned int* __restrict__ Yk, const unsigned int* __restrict__ Yv,
    const float* __restrict__ kb, const float* __restrict__ vb,
    const float* __restrict__ lng, const float* __restrict__ lnb,
    bf16* __restrict__ ks, bf16* __restrict__ vs) {
    const int t = threadIdx.x, lane = t & 63, wave = t >> 6;
    int orig = blockIdx.x;
    const bool vpath = orig >= M_ALL;
    if (vpath) orig -= M_ALL;
    {
        const int qc = M_ALL >> 3, rc = M_ALL & 7;
        const int xcd = orig & 7, sub = orig >> 3;
        orig = (xcd < rc ? xcd * (qc + 1) : rc * (qc + 1) + (xcd - rc) * qc) + sub;
    }
    const int m = orig;
    int mm = m < 700 ? m : m - 700;
    int base = m < 700 ? 0 : 200;
    int nsamp = mm / LT, l = mm - nsamp * LT;
    const unsigned int* Y = vpath ? Yv : Yk;
    const uint4* ya4 = (const uint4*)(Y + (size_t)(base + nsamp * 8 + TUP_A[l]) * (N2 / 2));
    const uint4* yb4 = (const uint4*)(Y + (size_t)(base + nsamp * 8 + TUP_B[l]) * (N2 / 2));
    if (vpath) {
        const float4* vb4 = (const float4*)vb;
        for (int u = t; u < OUTD / 4; u += 256) {       // 288 slots
            uint4 a4 = ya4[u], b4 = yb4[u];
            float4 c4 = vb4[u];
            ushort4 o;
            o.x = f2bits(ubits2f(a4.x & 0xFFFFu) + ubits2f(b4.x >> 16) + c4.x);
            o.y = f2bits(ubits2f(a4.y & 0xFFFFu) + ubits2f(b4.y >> 16) + c4.y);
            o.z = f2bits(ubits2f(a4.z & 0xFFFFu) + ubits2f(b4.z >> 16) + c4.z);
            o.w = f2bits(ubits2f(a4.w & 0xFFFFu) + ubits2f(b4.w >> 16) + c4.w);
            *(ushort4*)&vs[(size_t)m * OUTD + u * 4] = o;
        }
        return;
    }
    const float4* kb4 = (const float4*)kb;
    float vals[8];                                      // <= 2 iters x 4
    int cnt = 0;
    float s = 0.f, s2 = 0.f;
    for (int u = t; u < OUTD / 4; u += 256) {
        uint4 a4 = ya4[u], b4 = yb4[u];
        float4 c4 = kb4[u];
        float v0 = ubits2f(a4.x & 0xFFFFu) + ubits2f(b4.x >> 16) + c4.x;
        float v1 = ubits2f(a4.y & 0xFFFFu) + ubits2f(b4.y >> 16) + c4.y;
        float v2 = ubits2f(a4.z & 0xFFFFu) + ubits2f(b4.z >> 16) + c4.z;
        float v3 = ubits2f(a4.w & 0xFFFFu) + ubits2f(b4.w >> 16) + c4.w;
        vals[cnt] = v0; vals[cnt + 1] = v1; vals[cnt + 2] = v2; vals[cnt + 3] = v3;
        cnt += 4;
        s += (v0 + v1) + (v2 + v3);
        s2 += v0 * v0 + v1 * v1 + v2 * v2 + v3 * v3;
    }
    for (int o = 32; o > 0; o >>= 1) { s += __shfl_xor(s, o); s2 += __shfl_xor(s2, o); }
    __shared__ float r1[4], r2[4];
    if (lane == 0) { r1[wave] = s; r2[wave] = s2; }
    __syncthreads();
    s = r1[0] + r1[1] + r1[2] + r1[3];
    s2 = r2[0] + r2[1] + r2[2] + r2[3];
    float mu = s * (1.f / OUTD);
    float var = s2 * (1.f / OUTD) - mu * mu;
    float inv = rsqrtf(fmaxf(var, 0.f) + 1e-5f);
    const float4* lg4 = (const float4*)lng;
    const float4* lb4 = (const float4*)lnb;
    cnt = 0;
    for (int u = t; u < OUTD / 4; u += 256) {
        float4 g4 = lg4[u], b4v = lb4[u];
        ushort4 o;
        o.x = f2bits((vals[cnt]     - mu) * inv * g4.x + b4v.x);
        o.y = f2bits((vals[cnt + 1] - mu) * inv * g4.y + b4v.y);
        o.z = f2bits((vals[cnt + 2] - mu) * inv * g4.z + b4v.z);
        o.w = f2bits((vals[cnt + 3] - mu) * inv * g4.w + b4v.w);
        cnt += 4;
        *(ushort4*)&ks[(size_t)m * OUTD + u * 4] = o;
    }
}

// ---------------------------------------------------------------------------
// sv_k (merged softmax + vspad, one launch, 320 threads):
//  blocks [0,SM): softmax, one WAVE per (row, class), barrier-free
//    (140 = 64+64+12 lane-slots; attn as 5 x 144-col blocks, pad zeroed).
//  blocks [SM, SM+2880): vsp[w][d][j] = vs[w*140+j][d] (j>=140 -> 0);
//    block SM also zeroes gbuf.  2880*320 == 5*OUTD*KP exactly.
// ---------------------------------------------------------------------------
__global__ __launch_bounds__(320) void sv_k(const bf16* __restrict__ sc,
                                            bf16* __restrict__ attn,
                                            const bf16* __restrict__ vs,
                                            bf16* __restrict__ vp,
                                            float* __restrict__ gbuf) {
    const int t = threadIdx.x;
    if (blockIdx.x < SM) {
        const int row = blockIdx.x, w = t >> 6, lane = t & 63;
        const bf16* src = sc + (size_t)row * SN_PAD + w * 140;
        bf16* dst = attn + (size_t)row * ATT_STRIDE + w * ABLK;
        float a = bf2f(src[lane]);
        float b = bf2f(src[lane + 64]);        // lane+64 <= 127 < 140: valid
        float c = (lane < 12) ? bf2f(src[lane + 128]) : -3.0e38f;
        float m = fmaxf(fmaxf(a, b), c);
        for (int o = 32; o > 0; o >>= 1) m = fmaxf(m, __shfl_xor(m, o));
        float ea = __expf(a - m), eb = __expf(b - m);
        float ec = (lane < 12) ? __expf(c - m) : 0.f;
        float s = ea + eb + ec;
        for (int o = 32; o > 0; o >>= 1) s += __shfl_xor(s, o);
        float inv = 1.f / s;
        dst[lane] = f2bf(ea * inv);
        dst[lane + 64] = f2bf(eb * inv);
        if (lane < 16) dst[lane + 128] = f2bf(lane < 12 ? ec * inv : 0.f);
        return;
    }
    const int vb = blockIdx.x - SM;            // 0..2879
    if (vb == 0)
        for (int i = t; i < NQ * 21; i += 320) gbuf[i] = 0.f;
    int idx = vb * 320 + t;                    // < 921600 == 5*OUTD*KP
    int j = idx % KP;
    int rest = idx / KP;
    int dcol = rest % OUTD;
    int w = rest / OUTD;
    vp[idx] = (j < 140) ? vs[(size_t)(w * 140 + j) * OUTD + dcol] : f2bf(0.f);
}

// ---------------------------------------------------------------------------
// fproto_k v2: FUSED proto-GEMM + Gram reduction (r11/r12, verified).
// One block = one (query q, d-tile of 128).  Grid 1800, q-major XCD swizzle.
// A (attn rows) for ALL 5 classes staged once (50KB LDS, 2 barriers total);
// B (vsp) fragments read directly global->VGPR (zero cross-wave sharing;
// vsp L2-resident).  M=32 pads 28 real l-rows; l>=28 excluded from stats.
// K in [140,160) multiplies vsp's zero cols; max A read = attn row 5604
// (zeroed tail).  Epilogue: per-lane 21 stats, wave shfl + LDS reduce,
// 21 atomicAdds to gbuf[q*21..].  fp32 end-to-end.
// ---------------------------------------------------------------------------
__global__ __launch_bounds__(256) void fproto_k(
    const bf16* __restrict__ attn,   // [5632][720]
    const bf16* __restrict__ vsp,    // [5][1152][160]
    const bf16* __restrict__ vs,     // [6300][1152]
    float* __restrict__ gbuf) {      // [200][21]
    const int nwg = gridDim.x;       // 1800
    int orig = blockIdx.x;
    {
        const int qc = nwg >> 3, rc = nwg & 7;
        const int xcd = orig & 7, sub = orig >> 3;
        orig = (xcd < rc ? xcd * (qc + 1) : rc * (qc + 1) + (xcd - rc) * qc) + sub;
    }
    const int q = orig / 9, dt = orig - q * 9;
    const int t = threadIdx.x, lane = t & 63, wave = t >> 6;
    const int fr = lane & 15, quad = lane >> 4;

    __shared__ unsigned short As5[5 * 20 * 32 * 8];   // 51,200 B
    __shared__ float red[4][21];

    const unsigned short* attn_u = (const unsigned short*)attn;
    const unsigned short* vsp_u = (const unsigned short*)vsp;

    // stage ALL classes' A once: slot = w*640 + kq*32 + row  (3200 slots)
    for (int slot = t; slot < 3200; slot += 256) {
        int w = slot / 640, rem = slot - w * 640;
        int kq = rem >> 5, row = rem & 31;
        *(uint4*)&As5[slot * 8] =
            *(const uint4*)&attn_u[(size_t)(q * 28 + row) * ATT_STRIDE + w * ABLK + kq * 8];
    }
    __syncthreads();

    f32x4 acc[5][2][2];
#pragma unroll
    for (int w = 0; w < 5; w++)
#pragma unroll
        for (int i = 0; i < 2; i++)
#pragma unroll
            for (int j = 0; j < 2; j++) acc[w][i][j] = {0.f, 0.f, 0.f, 0.f};

    // per-lane B base: row (dt*128 + wave*32 + fr), kq-offset quad*8
    const unsigned short* vbase =
        vsp_u + (size_t)(dt * 128 + wave * 32 + fr) * KP + quad * 8;

#pragma unroll
    for (int w = 0; w < 5; w++) {
        s16x8 bfv[5][2];                        // issue all 10 loads up-front
#pragma unroll
        for (int s = 0; s < 5; s++)
#pragma unroll
            for (int j = 0; j < 2; j++)
                bfv[s][j] = *(const s16x8*)(vbase
                    + (size_t)w * OUTD * KP + (size_t)j * 16 * KP + s * 32);
#pragma unroll
        for (int s = 0; s < 5; s++) {
            s16x8 af[2];
#pragma unroll
            for (int i = 0; i < 2; i++)
                af[i] = *(const s16x8*)&As5[(w * 640 + (s * 4 + quad) * 32 + i * 16 + fr) * 8];
#pragma unroll
            for (int i = 0; i < 2; i++)
#pragma unroll
                for (int j = 0; j < 2; j++)
                    acc[w][i][j] = __builtin_amdgcn_mfma_f32_16x16x32_bf16(af[i], bfv[s][j], acc[w][i][j], 0, 0, 0);
        }
    }

    // ---- stats epilogue: C[l = i*16+quad*4+r][col = wave*32+j*16+fr] ----
    float st[21];
#pragma unroll
    for (int k = 0; k < 21; k++) st[k] = 0.f;
#pragma unroll
    for (int i = 0; i < 2; i++)
#pragma unroll
        for (int r = 0; r < 4; r++) {
            const int l = i * 16 + quad * 4 + r;
            if (l < 28) {
                const size_t vrow = (size_t)(700 + q * 28 + l) * OUTD;
#pragma unroll
                for (int j = 0; j < 2; j++) {
                    const int col = dt * 128 + wave * 32 + j * 16 + fr;
                    float v = bf2f(vs[vrow + col]);
                    float pv[5];
#pragma unroll
                    for (int w = 0; w < 5; w++) pv[w] = acc[w][i][j][r];
                    st[20] += v * v;
                    int c = 0;
#pragma unroll
                    for (int a = 0; a < 5; a++) {
                        st[15 + a] += v * pv[a];
#pragma unroll
                        for (int b = a; b < 5; b++) st[c++] += pv[a] * pv[b];
                    }
                }
            }
        }
#pragma unroll
    for (int k = 0; k < 21; k++)
        for (int o = 32; o > 0; o >>= 1) st[k] += __shfl_xor(st[k], o);
    if (lane == 0)
#pragma unroll
        for (int k = 0; k < 21; k++) red[wave][k] = st[k];
    __syncthreads();
    if (t < 21)
        atomicAdd(&gbuf[q * 21 + t], red[0][t] + red[1][t] + red[2][t] + red[3][t]);
}

// ---------------------------------------------------------------------------
// out (fp32): per q -> 25 sim + 5 ori
// ---------------------------------------------------------------------------
__global__ __launch_bounds__(64) void out_k(const float* __restrict__ gbuf,
                                            float* __restrict__ out) {
    int q = blockIdx.x;
    if (threadIdx.x != 0) return;
    const float* r = gbuf + q * 21;
    float G[5][5];
    int c = 0;
    for (int a = 0; a < 5; a++)
        for (int b = a; b < 5; b++) { G[a][b] = r[c]; G[b][a] = r[c]; c++; }
    float e = r[20];
    float nrm[5];
    for (int a = 0; a < 5; a++) nrm[a] = sqrtf(fmaxf(G[a][a], 0.f));
    for (int a = 0; a < 5; a++)
        for (int b = 0; b < 5; b++)
            out[(size_t)q * 25 + a * 5 + b] = G[a][b] / fmaxf(nrm[a] * nrm[b], 1e-8f);
    for (int w = 0; w < 5; w++)
        out[5000 + (size_t)q * 5 + w] = -(e - 2.f * r[15 + w] + G[w][w]) * (1.f / 28.f);
}

// ---------------------------------------------------------------------------
extern "C" void kernel_launch(void* const* d_in, const int* in_sizes, int n_in,
                              void* d_out, int out_size, void* d_ws, size_t ws_size,
                              hipStream_t stream) {
    const float* sup = (const float*)d_in[0];
    // d_in[1] = support_labels int32 — unused (sorted equal-shot)
    const float* qry = (const float*)d_in[2];
    const float* k_w = (const float*)d_in[3];
    const float* k_b = (const float*)d_in[4];
    const float* v_w = (const float*)d_in[5];
    const float* v_b = (const float*)d_in[6];
    const float* lng = (const float*)d_in[7];
    const float* lnb = (const float*)d_in[8];
    (void)in_sizes; (void)n_in; (void)out_size; (void)ws_size;

    // layout (bytes), peak 49,356,192 (<= verified ws_size >= 54.5 MB):
    //   pexb   @0           7,864,320 (1920 rows; 1800 real)  dead after proj
    //   wbf    @7,864,320  18,874,368 (k|v bf16)              dead after proj
    //   Yk     @26,738,688  8,294,400 (1800x2304)             dead after comb_k
    //   Yv     @35,033,088  8,294,400                         dead after comb_v
    //   ks     @0          14,588,928 (6332 rows; 6300 real)  dead after scores
    //   vs     @16,220,160 14,515,200 (6300 rows)             live to end
    //   sc     @30,735,360  8,650,752 (over dead Yk/Yv head)  dead after softmax
    //   vsp    @39,386,112  1,843,200
    //   attn   @41,229,312  8,110,080 (5632 rows x 720; 5 x 144-col blocks)
    //   gbuf   @49,339,392     16,800
    //   (pe table eliminated — prep_k computes PE inline)
    //   (protoc eliminated — fproto_k keeps proto in registers)
    char* ws = (char*)d_ws;
    bf16* pexb   = (bf16*)(ws + 0);
    bf16* wbf    = (bf16*)(ws + 7864320);
    bf16* Yk     = (bf16*)(ws + 26738688);
    bf16* Yv     = (bf16*)(ws + 35033088);
    bf16* ks     = (bf16*)(ws + 0);
    bf16* vs     = (bf16*)(ws + 16220160);
    bf16* sc     = (bf16*)(ws + 30735360);
    bf16* vsp    = (bf16*)(ws + 39386112);
    bf16* attn   = (bf16*)(ws + 41229312);
    float* gbuf  = (float*)(ws + 49339392);

    // merged wconv + pex (pex computes PE inline; also zeroes attn tail)
    prep_k<<<dim3(9216 + 1800), dim3(256), 0, stream>>>(
        (const float4*)k_w, (const float4*)v_w, (ushort4*)wbf,
        sup, qry, pexb, attn + (size_t)SM * ATT_STRIDE);

    // fused K+V projection: z in {k,v}; Y[1800,2304] = pexb @ W_view^T
    // TN=128 (r6/r8: 71.7us vs 84 at TN=64); BK=64 with r12's exact
    // per-instruction staging pattern -> only delta is half the barriers.
    gemm_bt<128><<<dim3(15, 18, 2), dim3(256), 0, stream>>>(
        pexb, DM, 0, wbf, DM, (size_t)4718592,
        1.0f, Yk, N2, (size_t)4147200, DM, 1800);

    combine_kv<<<dim3(2 * M_ALL), dim3(256), 0, stream>>>(
        (const unsigned int*)Yk, (const unsigned int*)Yv,
        k_b, v_b, lng, lnb, ks, vs);

    // scores: ks_q[5632,1152] @ ks_s[768,1152]^T / sqrt(1152)  (TN=64, r7)
    gemm_bt<64><<<dim3(44, 12, 1), dim3(256), 0, stream>>>(
        ks + (size_t)700 * OUTD, OUTD, 0, ks, OUTD, 0,
        0.029462782549439484f, sc, SN_PAD, 0, OUTD, 5632);

    // merged softmax (5600 blocks) + vspad (2880 blocks), 320 threads
    sv_k<<<dim3(SM + 2880), dim3(320), 0, stream>>>(sc, attn, vs, vsp, gbuf);

    // fused proto + Gram stats: one launch replaces 4x(gemm+gramred)
    fproto_k<<<dim3(1800), dim3(256), 0, stream>>>(attn, vsp, vs, gbuf);

    out_k<<<dim3(NQ), dim3(64), 0, stream>>>(gbuf, (float*)d_out);
}